// Round 3
// baseline (289.937 us; speedup 1.0000x reference)
//
#include <hip/hip_runtime.h>

// Problem constants (from reference)
#define BATCH   8
#define CIN     400
#define HH      128
#define WW      128
#define OBJ     50
#define CPG     8               // channels per group = 400/50
#define HWPIX   (HH * WW)       // 16384 pixels per plane
#define HW4     (HWPIX / 4)     // 4096 float4 per plane
#define BLOCK   256
#define F4_PER_THREAD 2
#define BLOCKS_PER_PLANE (HW4 / (BLOCK * F4_PER_THREAD))   // 8

// Native clang vector type — required by __builtin_nontemporal_store
typedef float vfloat4 __attribute__((ext_vector_type(4)));

// out[b,n,h,w] = sum_c f[b, n*CPG+c, h, w] * kernel[b, n, c]
__global__ __launch_bounds__(BLOCK) void dynhead_1x1_grouped(
    const float* __restrict__ f,
    const float* __restrict__ kern,
    float* __restrict__ out)
{
    // plane = b*OBJ + n   (0..399); 8 blocks per plane, 512 float4 per block
    const int plane = blockIdx.x / BLOCKS_PER_PLANE;
    const int chunk = blockIdx.x % BLOCKS_PER_PLANE;
    const int b = plane / OBJ;
    const int n = plane % OBJ;

    // Wave-uniform weight pointer -> scalar loads
    const float* __restrict__ wp = kern + (size_t)plane * CPG;
    float w[CPG];
#pragma unroll
    for (int c = 0; c < CPG; ++c) w[c] = wp[c];

    const int pix4 = chunk * (BLOCK * F4_PER_THREAD) + threadIdx.x;

    const vfloat4* __restrict__ fin =
        (const vfloat4*)(f + ((size_t)b * CIN + (size_t)n * CPG) * HWPIX) + pix4;

    // 16 independent 16B loads in flight (256 B/thread) — deep MLP
    vfloat4 v[CPG][F4_PER_THREAD];
#pragma unroll
    for (int c = 0; c < CPG; ++c)
#pragma unroll
        for (int j = 0; j < F4_PER_THREAD; ++j)
            v[c][j] = fin[(size_t)c * HW4 + j * BLOCK];

    vfloat4 acc[F4_PER_THREAD];
#pragma unroll
    for (int j = 0; j < F4_PER_THREAD; ++j)
        acc[j] = (vfloat4)(0.f);
#pragma unroll
    for (int c = 0; c < CPG; ++c) {
#pragma unroll
        for (int j = 0; j < F4_PER_THREAD; ++j)
            acc[j] += w[c] * v[c][j];
    }

    // Nontemporal: stream the output past L2/L3 so f stays L3-resident
    vfloat4* __restrict__ op = (vfloat4*)(out + (size_t)plane * HWPIX) + pix4;
#pragma unroll
    for (int j = 0; j < F4_PER_THREAD; ++j)
        __builtin_nontemporal_store(acc[j], op + j * BLOCK);
}

extern "C" void kernel_launch(void* const* d_in, const int* in_sizes, int n_in,
                              void* d_out, int out_size, void* d_ws, size_t ws_size,
                              hipStream_t stream)
{
    const float* f    = (const float*)d_in[0];   // [8,400,128,128]
    const float* kern = (const float*)d_in[1];   // [8,50,8,1,1]
    float* out        = (float*)d_out;           // [8,50,128,128]

    const int grid = BATCH * OBJ * BLOCKS_PER_PLANE;  // 8*50*8 = 3200
    dynhead_1x1_grouped<<<grid, BLOCK, 0, stream>>>(f, kern, out);
}

// Round 4
// 274.365 us; speedup vs baseline: 1.0568x; 1.0568x over previous
//
#include <hip/hip_runtime.h>

// Problem constants (from reference)
#define BATCH   8
#define CIN     400
#define HH      128
#define WW      128
#define OBJ     50
#define CPG     8               // channels per group = 400/50
#define HWPIX   (HH * WW)       // 16384 pixels per plane
#define HW4     (HWPIX / 4)     // 4096 float4 per plane
#define BLOCK   256
#define BLOCKS_PER_PLANE (HW4 / BLOCK)   // 16

// Native clang vector type — required by __builtin_nontemporal_* builtins
typedef float vfloat4 __attribute__((ext_vector_type(4)));

// out[b,n,h,w] = sum_c f[b, n*CPG+c, h, w] * kernel[b, n, c]
__global__ __launch_bounds__(BLOCK) void dynhead_1x1_grouped(
    const float* __restrict__ f,
    const float* __restrict__ kern,
    float* __restrict__ out)
{
    // plane = b*OBJ + n   (0..399); 16 blocks per plane
    const int plane = blockIdx.x / BLOCKS_PER_PLANE;
    const int chunk = blockIdx.x % BLOCKS_PER_PLANE;
    const int b = plane / OBJ;
    const int n = plane % OBJ;

    // Wave-uniform weight pointer -> scalar loads
    const float* __restrict__ wp = kern + (size_t)plane * CPG;
    float w[CPG];
#pragma unroll
    for (int c = 0; c < CPG; ++c) w[c] = wp[c];

    const int pix4 = chunk * BLOCK + threadIdx.x;   // float4 index in plane

    const vfloat4* __restrict__ fin =
        (const vfloat4*)(f + ((size_t)b * CIN + (size_t)n * CPG) * HWPIX) + pix4;

    // 8 independent 16B nontemporal loads — f has zero reuse, skip cache alloc
    vfloat4 v[CPG];
#pragma unroll
    for (int c = 0; c < CPG; ++c)
        v[c] = __builtin_nontemporal_load(fin + (size_t)c * HW4);

    vfloat4 acc = (vfloat4)(0.f);
#pragma unroll
    for (int c = 0; c < CPG; ++c)
        acc += w[c] * v[c];

    // Regular cached store (NT store measured neutral-to-negative in R3)
    vfloat4* __restrict__ op = (vfloat4*)(out + (size_t)plane * HWPIX) + pix4;
    *op = acc;
}

extern "C" void kernel_launch(void* const* d_in, const int* in_sizes, int n_in,
                              void* d_out, int out_size, void* d_ws, size_t ws_size,
                              hipStream_t stream)
{
    const float* f    = (const float*)d_in[0];   // [8,400,128,128]
    const float* kern = (const float*)d_in[1];   // [8,50,8,1,1]
    float* out        = (float*)d_out;           // [8,50,128,128]

    const int grid = BATCH * OBJ * BLOCKS_PER_PLANE;  // 8*50*16 = 6400
    dynhead_1x1_grouped<<<grid, BLOCK, 0, stream>>>(f, kern, out);
}